// Round 4
// baseline (56.007 us; speedup 1.0000x reference)
//
#include <hip/hip_runtime.h>

// Problem constants (fixed by reference setup_inputs)
constexpr int B_ = 32;
constexpr int S_ = 4096;
constexpr int D_ = 256;
constexpr int PAIRS_PER_BATCH = S_ - 1;                                   // 4095
constexpr int CHUNK = 16;                                                 // pairs per wave
constexpr int CHUNKS_PER_BATCH = (PAIRS_PER_BATCH + CHUNK - 1) / CHUNK;   // 256
constexpr int TOTAL_WAVES = B_ * CHUNKS_PER_BATCH;                        // 8192
constexpr int BLOCK = 256;
constexpr int WAVES_PER_BLOCK = BLOCK / 64;                               // 4
constexpr int GRID1 = TOTAL_WAVES / WAVES_PER_BLOCK;                      // 2048
constexpr int GROUP_SIZE = 64;                                            // blocks per group counter
constexpr int NGROUPS = GRID1 / GROUP_SIZE;                               // 32

// Single fused kernel. All cross-block communication is via device-scope
// atomic RMWs (coherent point; immune to per-XCD L2 staleness across graph
// replays). Completion detection uses (old % N == N-1) on monotonically
// increasing u32 counters: exactly one finisher per call for ANY initial
// value (0xAA poison safe), and 2^32 % N == 0 so wraparound is seamless.
// Output is a fixed-order sum of identical per-call partials -> bit-identical
// every call.
__global__ __launch_bounds__(BLOCK) void ccl_fused_kernel(
    const float* __restrict__ emb,
    const int* __restrict__ lab,
    float* __restrict__ out,
    unsigned int* __restrict__ partial_bits,  // GRID1 u32 (float bits)
    unsigned int* __restrict__ grp_cnt,       // NGROUPS u32
    unsigned int* __restrict__ glb_cnt) {     // 1 u32
  const int tid = threadIdx.x;
  const int lane = tid & 63;
  const int w = tid >> 6;
  const int wave = blockIdx.x * WAVES_PER_BLOCK + w;

  const int b = wave / CHUNKS_PER_BATCH;
  const int c = wave % CHUNKS_PER_BATCH;
  const int p0 = c * CHUNK;
  const int npairs = min(CHUNK, PAIRS_PER_BATCH - p0);   // 16 (15 for last chunk)

  const float4* __restrict__ rows =
      reinterpret_cast<const float4*>(emb + (size_t)b * S_ * D_);
  const int* __restrict__ lb = lab + b * S_;

  // --- Phase A: pair mask via ballot (one coalesced label read per wave) ---
  float wsum = 0.0f;
  int lv = 0;
  if (lane <= npairs) lv = lb[p0 + lane];
  const int nl = __shfl_down(lv, 1, 64);
  const bool m = (lane < npairs) && (lv != 0) && (lv == nl);
  const unsigned long long mask = __ballot(m);

  if (mask != 0ULL) {
    const unsigned long long rowmask = mask | (mask << 1);

    // --- Phase B: issue all needed row loads up front (high MLP) ---
    float4 r[CHUNK + 1];
    #pragma unroll
    for (int i = 0; i <= CHUNK; ++i) {
      if ((rowmask >> i) & 1ULL) {
        r[i] = rows[(size_t)(p0 + i) * (D_ / 4) + lane];
      }
    }

    // --- Phase C: reduce each masked pair ---
    #pragma unroll
    for (int i = 0; i < CHUNK; ++i) {
      if ((mask >> i) & 1ULL) {
        const float dx = r[i].x - r[i + 1].x;
        const float dy = r[i].y - r[i + 1].y;
        const float dz = r[i].z - r[i + 1].z;
        const float dw = r[i].w - r[i + 1].w;
        float s = dx * dx + dy * dy + dz * dz + dw * dw;
        #pragma unroll
        for (int xm = 1; xm < 64; xm <<= 1) s += __shfl_xor(s, xm, 64);
        wsum += sqrtf(s);
      }
    }
  }

  // --- Block partial via atomic exchange (coherent-point write) ---
  __shared__ float lds[WAVES_PER_BLOCK];
  __shared__ unsigned int last_s;
  if (lane == 0) lds[w] = wsum;
  __syncthreads();

  if (tid == 0) {
    float bsum = 0.0f;
    #pragma unroll
    for (int i = 0; i < WAVES_PER_BLOCK; ++i) bsum += lds[i];
    atomicExch(&partial_bits[blockIdx.x], __float_as_uint(bsum));
    __threadfence();
    unsigned int flag = 0;
    const unsigned int o1 = atomicAdd(&grp_cnt[blockIdx.x / GROUP_SIZE], 1u);
    if ((o1 % GROUP_SIZE) == GROUP_SIZE - 1) {
      __threadfence();   // keep the release chain intact at the group link
      const unsigned int o2 = atomicAdd(glb_cnt, 1u);
      if ((o2 % NGROUPS) == NGROUPS - 1) flag = 1;
    }
    last_s = flag;
  }
  __syncthreads();
  if (last_s == 0) return;

  // --- Finisher: unique last block; atomic-RMW reads (coherent, no stale L2)
  __threadfence();
  float s = 0.0f;
  for (int i = tid; i < GRID1; i += BLOCK) {   // 8 each, fixed order
    s += __uint_as_float(atomicAdd(&partial_bits[i], 0u));
  }
  #pragma unroll
  for (int xm = 1; xm < 64; xm <<= 1) s += __shfl_xor(s, xm, 64);

  __shared__ float lds2[WAVES_PER_BLOCK];
  if (lane == 0) lds2[w] = s;
  __syncthreads();
  if (tid == 0) {
    float t = 0.0f;
    #pragma unroll
    for (int i = 0; i < WAVES_PER_BLOCK; ++i) t += lds2[i];
    out[0] = t / (float)((long long)B_ * S_);
  }
}

extern "C" void kernel_launch(void* const* d_in, const int* in_sizes, int n_in,
                              void* d_out, int out_size, void* d_ws, size_t ws_size,
                              hipStream_t stream) {
  const float* emb = (const float*)d_in[0];
  const int* lab = (const int*)d_in[1];
  float* out = (float*)d_out;

  char* ws = (char*)d_ws;
  unsigned int* partial_bits = (unsigned int*)ws;                 // 8 KiB
  unsigned int* grp_cnt = (unsigned int*)(ws + GRID1 * sizeof(unsigned int));
  unsigned int* glb_cnt = grp_cnt + NGROUPS;

  ccl_fused_kernel<<<GRID1, BLOCK, 0, stream>>>(emb, lab, out, partial_bits,
                                                grp_cnt, glb_cnt);
}

// Round 6
// 22.869 us; speedup vs baseline: 2.4490x; 2.4490x over previous
//
#include <hip/hip_runtime.h>

// Problem constants (fixed by reference setup_inputs)
constexpr int B_ = 32;
constexpr int S_ = 4096;
constexpr int D_ = 256;
constexpr int PAIRS_PER_BATCH = S_ - 1;                                   // 4095
constexpr int CHUNK = 16;                                                 // pairs per wave
constexpr int CHUNKS_PER_BATCH = (PAIRS_PER_BATCH + CHUNK - 1) / CHUNK;   // 256
constexpr int TOTAL_WAVES = B_ * CHUNKS_PER_BATCH;                        // 8192
constexpr int BLOCK = 256;
constexpr int WAVES_PER_BLOCK = BLOCK / 64;                               // 4
constexpr int GRID1 = TOTAL_WAVES / WAVES_PER_BLOCK;                      // 2048

// Kernel 1: each wave handles CHUNK consecutive pairs of one batch row.
// Phase A: one coalesced label read + ballot -> wave-uniform pair mask.
// Phase B: 17 UNCONDITIONAL row loads (address predicated: unneeded slots
//          re-read the wave's first needed row -> L1 hit, no extra HBM).
//          sched_barrier(0) pins all loads BEFORE any use, forcing the
//          compiler to keep 17 float4 in flight (MLP=17) instead of
//          sinking each load to its use (round-2/4 showed VGPR=40 => sunk).
// Phase C: per masked pair, diff + 64-lane butterfly + sqrt, accumulate.
__global__ __launch_bounds__(BLOCK) void ccl_partial_kernel(
    const float* __restrict__ emb,
    const int* __restrict__ lab,
    float* __restrict__ partial) {
  const int wave = (blockIdx.x * BLOCK + threadIdx.x) >> 6;
  const int lane = threadIdx.x & 63;

  const int b = wave / CHUNKS_PER_BATCH;
  const int c = wave % CHUNKS_PER_BATCH;
  const int p0 = c * CHUNK;
  const int npairs = min(CHUNK, PAIRS_PER_BATCH - p0);   // 16 (15 for last chunk)

  const float4* __restrict__ rows =
      reinterpret_cast<const float4*>(emb + (size_t)b * S_ * D_);
  const int* __restrict__ lb = lab + b * S_;

  // --- Phase A: mask via ballot (one coalesced 68B label read per wave) ---
  int lv = 0;
  if (lane <= npairs) lv = lb[p0 + lane];     // labels p0 .. p0+npairs
  const int nl = __shfl_down(lv, 1, 64);      // label at p0+lane+1
  const bool m = (lane < npairs) && (lv != 0) && (lv == nl);
  const unsigned long long mask = __ballot(m);          // bit i = pair p0+i masked
  if (mask == 0ULL) {
    if (lane == 0) partial[wave] = 0.0f;
    return;
  }
  const unsigned long long rowmask = mask | (mask << 1); // bit i = row p0+i needed
  const int firstrow = (int)__builtin_ctzll(rowmask);    // <= 15; in-bounds always

  // --- Phase B: 17 unconditional, independent loads (predicated address) ---
  float4 r[CHUNK + 1];
  #pragma unroll
  for (int i = 0; i <= CHUNK; ++i) {
    // bit 16 of rowmask is 0 whenever p0+16 would be out of range (last chunk
    // has npairs=15 -> mask bits 0..14 -> rowmask bits 0..15), so the real
    // address is always valid; dead slots alias the first needed row.
    const int row = ((rowmask >> i) & 1ULL) ? (p0 + i) : (p0 + firstrow);
    r[i] = rows[(size_t)row * (D_ / 4) + lane];
  }
  __builtin_amdgcn_sched_barrier(0);   // do NOT sink loads into Phase C

  // --- Phase C: reduce each masked pair ---
  float wsum = 0.0f;
  #pragma unroll
  for (int i = 0; i < CHUNK; ++i) {
    if ((mask >> i) & 1ULL) {
      const float dx = r[i].x - r[i + 1].x;
      const float dy = r[i].y - r[i + 1].y;
      const float dz = r[i].z - r[i + 1].z;
      const float dw = r[i].w - r[i + 1].w;
      float s = dx * dx + dy * dy + dz * dz + dw * dw;
      #pragma unroll
      for (int xm = 1; xm < 64; xm <<= 1) s += __shfl_xor(s, xm, 64);
      wsum += sqrtf(s);
    }
  }

  if (lane == 0) partial[wave] = wsum;
}

// Kernel 2: deterministic fixed-order reduction of the 8192 wave partials.
__global__ __launch_bounds__(BLOCK) void ccl_reduce_kernel(
    const float* __restrict__ partial, float* __restrict__ out) {
  float s = 0.0f;
  for (int i = threadIdx.x; i < TOTAL_WAVES; i += BLOCK) s += partial[i];

  #pragma unroll
  for (int xm = 1; xm < 64; xm <<= 1) s += __shfl_xor(s, xm, 64);

  __shared__ float lds[WAVES_PER_BLOCK];
  const int lane = threadIdx.x & 63;
  const int w = threadIdx.x >> 6;
  if (lane == 0) lds[w] = s;
  __syncthreads();

  if (threadIdx.x == 0) {
    float t = 0.0f;
    #pragma unroll
    for (int i = 0; i < WAVES_PER_BLOCK; ++i) t += lds[i];
    out[0] = t / (float)((long long)B_ * S_);
  }
}

extern "C" void kernel_launch(void* const* d_in, const int* in_sizes, int n_in,
                              void* d_out, int out_size, void* d_ws, size_t ws_size,
                              hipStream_t stream) {
  const float* emb = (const float*)d_in[0];
  const int* lab = (const int*)d_in[1];
  float* out = (float*)d_out;
  float* partial = (float*)d_ws;   // TOTAL_WAVES floats = 32 KiB

  ccl_partial_kernel<<<GRID1, BLOCK, 0, stream>>>(emb, lab, partial);
  ccl_reduce_kernel<<<1, BLOCK, 0, stream>>>(partial, out);
}